// Round 6
// baseline (264.966 us; speedup 1.0000x reference)
//
#include <hip/hip_runtime.h>
#include <hip/hip_bf16.h>
#include <hip/hip_cooperative_groups.h>

namespace cg = cooperative_groups;

#define BATCH 1024
#define INPUT_DIM 1024
#define NBK 32
#define KDIM 16

typedef __attribute__((ext_vector_type(8))) short short8;
typedef __attribute__((ext_vector_type(8))) unsigned short ushort8;
typedef __attribute__((ext_vector_type(4))) float f32x4;

static __device__ __forceinline__ unsigned short f2bf(float f) {
    union { float f; unsigned u; } v; v.f = f;
    unsigned r = v.u + 0x7fffu + ((v.u >> 16) & 1u);   // RNE
    return (unsigned short)(r >> 16);
}

// ===========================================================================
// Shared phase bodies (used by both the fused cooperative kernel and the
// 4-kernel fallback). All mappings identical to the Round-4 PASSING kernels.
// ===========================================================================

__device__ __forceinline__ void prep_x_task(const float* __restrict__ x,
                                            unsigned short* __restrict__ xb,
                                            float* __restrict__ out,
                                            int blk, int tid) {
    const int i = (blk * 256 + tid) * 8;
    float4 v0 = *(const float4*)(x + i);
    float4 v1 = *(const float4*)(x + i + 4);
    ushort8 o;
    o[0] = f2bf(v0.x); o[1] = f2bf(v0.y); o[2] = f2bf(v0.z); o[3] = f2bf(v0.w);
    o[4] = f2bf(v1.x); o[5] = f2bf(v1.y); o[6] = f2bf(v1.z); o[7] = f2bf(v1.w);
    *(ushort8*)(xb + i) = o;
    const int b = i >> 10;
    const int d = i & 1023;
    float* op = out + b * 1056 + d;
    *(float4*)(op)     = v0;
    *(float4*)(op + 4) = v1;
}

__device__ __forceinline__ void prep_w_task(const float* __restrict__ W,
                                            unsigned short* __restrict__ wt,
                                            int b2, int tid) {
    const int k  = b2 >> 2;                    // 0..31
    const int d  = (b2 & 3) * 256 + tid;
    const float* src = W + (k * INPUT_DIM + d) * KDIM;  // 16 contiguous floats
    float4 v0 = *(const float4*)(src + 0);
    float4 v1 = *(const float4*)(src + 4);
    float4 v2 = *(const float4*)(src + 8);
    float4 v3 = *(const float4*)(src + 12);
    unsigned short* dst = wt + k * (KDIM * INPUT_DIM) + d;  // stride 1024 per m
    dst[0 * INPUT_DIM]  = f2bf(v0.x); dst[1 * INPUT_DIM]  = f2bf(v0.y);
    dst[2 * INPUT_DIM]  = f2bf(v0.z); dst[3 * INPUT_DIM]  = f2bf(v0.w);
    dst[4 * INPUT_DIM]  = f2bf(v1.x); dst[5 * INPUT_DIM]  = f2bf(v1.y);
    dst[6 * INPUT_DIM]  = f2bf(v1.z); dst[7 * INPUT_DIM]  = f2bf(v1.w);
    dst[8 * INPUT_DIM]  = f2bf(v2.x); dst[9 * INPUT_DIM]  = f2bf(v2.y);
    dst[10 * INPUT_DIM] = f2bf(v2.z); dst[11 * INPUT_DIM] = f2bf(v2.w);
    dst[12 * INPUT_DIM] = f2bf(v3.x); dst[13 * INPUT_DIM] = f2bf(v3.y);
    dst[14 * INPUT_DIM] = f2bf(v3.z); dst[15 * INPUT_DIM] = f2bf(v3.w);
}

// gemm tile: 4 waves split d 4-way (8 slabs of 32 each), LDS reduce.
// tile t: k = t>>5, b0 = (t&31)*32. lds needs 1536 floats.
__device__ __forceinline__ void gemm_tile(const unsigned short* __restrict__ xb,
                                          const unsigned short* __restrict__ wt,
                                          float* __restrict__ act2,
                                          float* lds, int t, int tid) {
    const int k    = t >> 5;
    const int b0   = (t & 31) * 32;
    const int lane = tid & 63;
    const int w4   = tid >> 6;                 // 0..3: d-quarter
    const int m16  = lane & 15;
    const int quad = lane >> 4;

    const unsigned short* a0p = xb + (b0 + m16) * INPUT_DIM + w4 * 256 + quad * 8;
    const unsigned short* a1p = a0p + 16 * INPUT_DIM;
    const unsigned short* bp  = wt + k * (KDIM * INPUT_DIM) + m16 * INPUT_DIM
                                   + w4 * 256 + quad * 8;

    f32x4 acc0 = {0.f, 0.f, 0.f, 0.f};
    f32x4 acc1 = {0.f, 0.f, 0.f, 0.f};

    short8 A0 = *(const short8*)a0p;
    short8 A1 = *(const short8*)a1p;
    short8 BV = *(const short8*)bp;

#pragma unroll
    for (int s = 0; s < 8; ++s) {
        const int sp = (s < 7) ? (s + 1) * 32 : 0;   // wrap: dead value, in-bounds
        short8 nA0 = *(const short8*)(a0p + sp);
        short8 nA1 = *(const short8*)(a1p + sp);
        short8 nBV = *(const short8*)(bp + sp);
        acc0 = __builtin_amdgcn_mfma_f32_16x16x32_bf16(A0, BV, acc0, 0, 0, 0);
        acc1 = __builtin_amdgcn_mfma_f32_16x16x32_bf16(A1, BV, acc1, 0, 0, 0);
        A0 = nA0; A1 = nA1; BV = nBV;
    }

    if (w4 > 0) {
        float* r = &lds[(w4 - 1) * 512 + lane * 8];
        *(float4*)(r)     = make_float4(acc0[0], acc0[1], acc0[2], acc0[3]);
        *(float4*)(r + 4) = make_float4(acc1[0], acc1[1], acc1[2], acc1[3]);
    }
    __syncthreads();
    if (w4 == 0) {
#pragma unroll
        for (int j = 0; j < 3; ++j) {
            const float* r = &lds[j * 512 + lane * 8];
            float4 p0 = *(const float4*)(r);
            float4 p1 = *(const float4*)(r + 4);
            acc0[0] += p0.x; acc0[1] += p0.y; acc0[2] += p0.z; acc0[3] += p0.w;
            acc1[0] += p1.x; acc1[1] += p1.y; acc1[2] += p1.z; acc1[3] += p1.w;
        }
        const int row0 = b0 + quad * 4;        // C/D: col=lane&15, row=quad*4+r
#pragma unroll
        for (int r = 0; r < 4; ++r) {
            act2[(k * BATCH + row0 + r) * KDIM + m16]      = acc0[r];
            act2[(k * BATCH + row0 + 16 + r) * KDIM + m16] = acc1[r];
        }
    }
}

// pairwise tile: t: k = t>>5, chunk = t&31. lds needs 512 floats.
__device__ __forceinline__ void pairwise_tile(const float* __restrict__ act2,
                                              float* __restrict__ part,
                                              float* lds, int t, int tid) {
    const int k  = t >> 5;
    const int c0 = (t & 31) * 32;
    const float* base = act2 + k * (BATCH * KDIM);

    if (tid < 128) ((float4*)lds)[tid] = ((const float4*)(base + c0 * KDIM))[tid];

    float a[4][16];
#pragma unroll
    for (int r = 0; r < 4; ++r) {
#pragma unroll
        for (int i = 0; i < 4; ++i) {
            float4 v = *(const float4*)(base + (tid + r * 256) * KDIM + i * 4);
            a[r][i * 4 + 0] = v.x; a[r][i * 4 + 1] = v.y;
            a[r][i * 4 + 2] = v.z; a[r][i * 4 + 3] = v.w;
        }
    }
    __syncthreads();

    float f0 = 0.f, f1 = 0.f, f2 = 0.f, f3 = 0.f;
#pragma unroll 2
    for (int c = 0; c < 32; ++c) {
        const float4 r0 = *(const float4*)&lds[c * 16 + 0];
        const float4 r1 = *(const float4*)&lds[c * 16 + 4];
        const float4 r2 = *(const float4*)&lds[c * 16 + 8];
        const float4 r3 = *(const float4*)&lds[c * 16 + 12];
#define ROWSUM(rr)                                                           \
        (fabsf(a[rr][0]  - r0.x) + fabsf(a[rr][1]  - r0.y) +                 \
         fabsf(a[rr][2]  - r0.z) + fabsf(a[rr][3]  - r0.w) +                 \
         fabsf(a[rr][4]  - r1.x) + fabsf(a[rr][5]  - r1.y) +                 \
         fabsf(a[rr][6]  - r1.z) + fabsf(a[rr][7]  - r1.w) +                 \
         fabsf(a[rr][8]  - r2.x) + fabsf(a[rr][9]  - r2.y) +                 \
         fabsf(a[rr][10] - r2.z) + fabsf(a[rr][11] - r2.w) +                 \
         fabsf(a[rr][12] - r3.x) + fabsf(a[rr][13] - r3.y) +                 \
         fabsf(a[rr][14] - r3.z) + fabsf(a[rr][15] - r3.w))
        f0 += __expf(-ROWSUM(0));
        f1 += __expf(-ROWSUM(1));
        f2 += __expf(-ROWSUM(2));
        f3 += __expf(-ROWSUM(3));
#undef ROWSUM
    }
    float* p = part + (t & 31) * (NBK * BATCH) + k * BATCH + tid;
    p[0]   = f0;
    p[256] = f1;
    p[512] = f2;
    p[768] = f3;
}

__device__ __forceinline__ void combine_task(const float* __restrict__ part,
                                             float* __restrict__ out,
                                             int blk, int tid) {
    const int t = blk * 256 + tid;             // k*1024 + b, t < 32768
    const int k = t >> 10;
    const int b = t & 1023;
    float s = 0.f;
#pragma unroll
    for (int i = 0; i < 32; ++i) s += part[i * (NBK * BATCH) + t];
    out[b * 1056 + 1024 + k] = s;
}

// ===========================================================================
// Fused cooperative kernel: 512 blocks x 256 thr (2 blocks/CU — safe
// co-residency margin; R5's 1024-block version was rejected TooLarge).
// Each phase loops 2 tiles. grid.sync() between phases.
// ===========================================================================
__global__ __launch_bounds__(256, 2) void fused(const float* __restrict__ x,
                                                const float* __restrict__ W,
                                                unsigned short* __restrict__ xb,
                                                unsigned short* __restrict__ wt,
                                                float* __restrict__ act2,
                                                float* __restrict__ part,
                                                float* __restrict__ out) {
    cg::grid_group grid = cg::this_grid();
    __shared__ float lds[1536];   // 6 KB
    const int bid = blockIdx.x;
    const int tid = threadIdx.x;

    // Phase 1: every block does one x-chunk; blocks <128 also one W-chunk.
    prep_x_task(x, xb, out, bid, tid);
    if (bid < 128) prep_w_task(W, wt, bid, tid);

    grid.sync();

    // Phase 2: 1024 gemm tiles over 512 blocks.
    gemm_tile(xb, wt, act2, lds, bid, tid);
    __syncthreads();
    gemm_tile(xb, wt, act2, lds, bid + 512, tid);

    grid.sync();

    // Phase 3: 1024 pairwise tiles over 512 blocks.
    pairwise_tile(act2, part, lds, bid, tid);
    __syncthreads();
    pairwise_tile(act2, part, lds, bid + 512, tid);

    grid.sync();

    // Phase 4: 128 combine tasks.
    if (bid < 128) combine_task(part, out, bid, tid);
}

// ===========================================================================
// Fallback kernels (Round-4 structure, known passing) — used only if the
// cooperative launch is rejected.
// ===========================================================================
__global__ __launch_bounds__(256) void prep_k(const float* __restrict__ x,
                                              const float* __restrict__ W,
                                              unsigned short* __restrict__ xb,
                                              unsigned short* __restrict__ wt,
                                              float* __restrict__ out) {
    if (blockIdx.x < 512) prep_x_task(x, xb, out, blockIdx.x, threadIdx.x);
    else                  prep_w_task(W, wt, blockIdx.x - 512, threadIdx.x);
}

__global__ __launch_bounds__(256) void gemm_k(const unsigned short* __restrict__ xb,
                                              const unsigned short* __restrict__ wt,
                                              float* __restrict__ act2) {
    __shared__ float lds[1536];
    gemm_tile(xb, wt, act2, lds, blockIdx.x, threadIdx.x);
}

__global__ __launch_bounds__(256) void pairwise_k(const float* __restrict__ act2,
                                                  float* __restrict__ part) {
    __shared__ float lds[512];
    pairwise_tile(act2, part, lds, blockIdx.x, threadIdx.x);
}

__global__ __launch_bounds__(256) void combine_k(const float* __restrict__ part,
                                                 float* __restrict__ out) {
    combine_task(part, out, blockIdx.x, threadIdx.x);
}

extern "C" void kernel_launch(void* const* d_in, const int* in_sizes, int n_in,
                              void* d_out, int out_size, void* d_ws, size_t ws_size,
                              hipStream_t stream) {
    const float* x = (const float*)d_in[0];
    const float* W = (const float*)d_in[1];
    float* out = (float*)d_out;

    unsigned short* xb = (unsigned short*)d_ws;                        // 2 MB
    unsigned short* wt = (unsigned short*)((char*)d_ws + 2*1024*1024); // 1 MB
    float* act2 = (float*)((char*)d_ws + 3 * 1024 * 1024);             // 2 MB
    float* part = (float*)((char*)d_ws + 5 * 1024 * 1024);             // 4 MB

    void* args[] = {(void*)&x, (void*)&W, (void*)&xb, (void*)&wt,
                    (void*)&act2, (void*)&part, (void*)&out};
    hipError_t err = hipLaunchCooperativeKernel((void*)fused, dim3(512), dim3(256),
                                                args, 0, stream);
    if (err != hipSuccess) {
        // Fallback: 4 ordinary kernels (identical math, known passing).
        prep_k<<<640, 256, 0, stream>>>(x, W, xb, wt, out);
        gemm_k<<<1024, 256, 0, stream>>>(xb, wt, act2);
        pairwise_k<<<1024, 256, 0, stream>>>(act2, part);
        combine_k<<<128, 256, 0, stream>>>(part, out);
    }
}

// Round 7
// 162.237 us; speedup vs baseline: 1.6332x; 1.6332x over previous
//
#include <hip/hip_runtime.h>
#include <hip/hip_bf16.h>

#define BATCH 1024
#define INPUT_DIM 1024
#define NBK 32
#define KDIM 16

typedef __attribute__((ext_vector_type(8))) short short8;
typedef __attribute__((ext_vector_type(4))) float f32x4;

static __device__ __forceinline__ unsigned short f2bf(float f) {
    union { float f; unsigned u; } v; v.f = f;
    unsigned r = v.u + 0x7fffu + ((v.u >> 16) & 1u);   // RNE
    return (unsigned short)(r >> 16);
}

// ---------------------------------------------------------------------------
// Kernel 1: act2[k][b][m] = sum_d x[b][d]*W[k][d][m], bf16 MFMA 16x16x32,
// reading x and W DIRECTLY in fp32 (in-register bf16 convert — no prep pass,
// no staging arrays). Grid (k*32 + btile) = 1024 blocks x 256 thr (4 waves);
// waves split d 4-way (8 slabs of 32), LDS cross-wave reduce (R4-proven).
// Side jobs: each block copies a 4 KB slice of x -> out[b][0:1024] and
// zeroes its 32 out-feature slots (so pairwise can atomicAdd).
// A lane: x[(b0+(lane&15))][d0 + (lane>>4)*8 + j]       (validated layout)
// B lane: W[k][d0+(lane>>4)*8+j][lane&15]               (validated layout)
// C/D: col=lane&15, row=(lane>>4)*4+reg                 (validated layout)
// ---------------------------------------------------------------------------
__global__ __launch_bounds__(256) void gemm_k(const float* __restrict__ x,
                                              const float* __restrict__ W,
                                              float* __restrict__ act2,
                                              float* __restrict__ out) {
    __shared__ float lds[1536];
    const int bid  = blockIdx.x;
    const int tid  = threadIdx.x;
    const int k    = bid >> 5;
    const int b0   = (bid & 31) * 32;
    const int lane = tid & 63;
    const int w4   = tid >> 6;                 // 0..3: d-quarter
    const int m16  = lane & 15;
    const int quad = lane >> 4;

    // side job 1: copy x slice into out (each block: 4 KB, disjoint)
    {
        const int i = bid * 1024 + tid * 4;    // covers all 1M x elements once
        float4 v = *(const float4*)(x + i);
        const int b = i >> 10;
        const int d = i & 1023;
        *(float4*)(out + b * 1056 + d) = v;
    }
    // side job 2: zero this block's 32 feature slots (k, b0..b0+31)
    if (tid < 32) out[(b0 + tid) * 1056 + 1024 + k] = 0.f;

    const float* xa0 = x + (b0 + m16) * INPUT_DIM + w4 * 256 + quad * 8;
    const float* xa1 = xa0 + 16 * INPUT_DIM;
    const float* wb  = W + k * (INPUT_DIM * KDIM) + (w4 * 256 + quad * 8) * KDIM + m16;

    f32x4 acc0 = {0.f, 0.f, 0.f, 0.f};
    f32x4 acc1 = {0.f, 0.f, 0.f, 0.f};

#pragma unroll
    for (int s = 0; s < 8; ++s) {
        const float* pa0 = xa0 + s * 32;
        const float* pa1 = xa1 + s * 32;
        const float* pb  = wb + s * 32 * KDIM;
        float4 a0l = *(const float4*)(pa0);
        float4 a0h = *(const float4*)(pa0 + 4);
        float4 a1l = *(const float4*)(pa1);
        float4 a1h = *(const float4*)(pa1 + 4);
        float bw0 = pb[0 * KDIM], bw1 = pb[1 * KDIM];
        float bw2 = pb[2 * KDIM], bw3 = pb[3 * KDIM];
        float bw4 = pb[4 * KDIM], bw5 = pb[5 * KDIM];
        float bw6 = pb[6 * KDIM], bw7 = pb[7 * KDIM];
        short8 A0, A1, BV;
        A0[0] = (short)f2bf(a0l.x); A0[1] = (short)f2bf(a0l.y);
        A0[2] = (short)f2bf(a0l.z); A0[3] = (short)f2bf(a0l.w);
        A0[4] = (short)f2bf(a0h.x); A0[5] = (short)f2bf(a0h.y);
        A0[6] = (short)f2bf(a0h.z); A0[7] = (short)f2bf(a0h.w);
        A1[0] = (short)f2bf(a1l.x); A1[1] = (short)f2bf(a1l.y);
        A1[2] = (short)f2bf(a1l.z); A1[3] = (short)f2bf(a1l.w);
        A1[4] = (short)f2bf(a1h.x); A1[5] = (short)f2bf(a1h.y);
        A1[6] = (short)f2bf(a1h.z); A1[7] = (short)f2bf(a1h.w);
        BV[0] = (short)f2bf(bw0);   BV[1] = (short)f2bf(bw1);
        BV[2] = (short)f2bf(bw2);   BV[3] = (short)f2bf(bw3);
        BV[4] = (short)f2bf(bw4);   BV[5] = (short)f2bf(bw5);
        BV[6] = (short)f2bf(bw6);   BV[7] = (short)f2bf(bw7);
        acc0 = __builtin_amdgcn_mfma_f32_16x16x32_bf16(A0, BV, acc0, 0, 0, 0);
        acc1 = __builtin_amdgcn_mfma_f32_16x16x32_bf16(A1, BV, acc1, 0, 0, 0);
    }

    // cross-wave reduce (d-quarters) via LDS, wave0 writes
    if (w4 > 0) {
        float* r = &lds[(w4 - 1) * 512 + lane * 8];
        *(float4*)(r)     = make_float4(acc0[0], acc0[1], acc0[2], acc0[3]);
        *(float4*)(r + 4) = make_float4(acc1[0], acc1[1], acc1[2], acc1[3]);
    }
    __syncthreads();
    if (w4 == 0) {
#pragma unroll
        for (int j = 0; j < 3; ++j) {
            const float* r = &lds[j * 512 + lane * 8];
            float4 p0 = *(const float4*)(r);
            float4 p1 = *(const float4*)(r + 4);
            acc0[0] += p0.x; acc0[1] += p0.y; acc0[2] += p0.z; acc0[3] += p0.w;
            acc1[0] += p1.x; acc1[1] += p1.y; acc1[2] += p1.z; acc1[3] += p1.w;
        }
        const int row0 = b0 + quad * 4;
#pragma unroll
        for (int r = 0; r < 4; ++r) {
            act2[(k * BATCH + row0 + r) * KDIM + m16]      = acc0[r];
            act2[(k * BATCH + row0 + 16 + r) * KDIM + m16] = acc1[r];
        }
    }
}

// ---------------------------------------------------------------------------
// Kernel 2: pairwise features, 4 b-rows/thread, atomicAdd straight into out.
// grid = (chunk=32, k=32) = 1024 blocks x 256 thr. 32 c-rows in LDS
// (all-lane broadcast reads, conflict-free). No part buffer, no combine pass.
// ---------------------------------------------------------------------------
__global__ __launch_bounds__(256) void pairwise_k(const float* __restrict__ act2,
                                                  float* __restrict__ out) {
    __shared__ float cs[32 * KDIM];  // 2 KB
    const int tid = threadIdx.x;
    const int k   = blockIdx.y;
    const int c0  = blockIdx.x * 32;
    const float* base = act2 + k * (BATCH * KDIM);

    if (tid < 128) ((float4*)cs)[tid] = ((const float4*)(base + c0 * KDIM))[tid];

    float a[4][16];
#pragma unroll
    for (int r = 0; r < 4; ++r) {
#pragma unroll
        for (int i = 0; i < 4; ++i) {
            float4 v = *(const float4*)(base + (tid + r * 256) * KDIM + i * 4);
            a[r][i * 4 + 0] = v.x; a[r][i * 4 + 1] = v.y;
            a[r][i * 4 + 2] = v.z; a[r][i * 4 + 3] = v.w;
        }
    }
    __syncthreads();

    float f0 = 0.f, f1 = 0.f, f2 = 0.f, f3 = 0.f;
#pragma unroll 2
    for (int c = 0; c < 32; ++c) {
        const float4 r0 = *(const float4*)&cs[c * 16 + 0];
        const float4 r1 = *(const float4*)&cs[c * 16 + 4];
        const float4 r2 = *(const float4*)&cs[c * 16 + 8];
        const float4 r3 = *(const float4*)&cs[c * 16 + 12];
#define ROWSUM(rr)                                                           \
        (fabsf(a[rr][0]  - r0.x) + fabsf(a[rr][1]  - r0.y) +                 \
         fabsf(a[rr][2]  - r0.z) + fabsf(a[rr][3]  - r0.w) +                 \
         fabsf(a[rr][4]  - r1.x) + fabsf(a[rr][5]  - r1.y) +                 \
         fabsf(a[rr][6]  - r1.z) + fabsf(a[rr][7]  - r1.w) +                 \
         fabsf(a[rr][8]  - r2.x) + fabsf(a[rr][9]  - r2.y) +                 \
         fabsf(a[rr][10] - r2.z) + fabsf(a[rr][11] - r2.w) +                 \
         fabsf(a[rr][12] - r3.x) + fabsf(a[rr][13] - r3.y) +                 \
         fabsf(a[rr][14] - r3.z) + fabsf(a[rr][15] - r3.w))
        f0 += __expf(-ROWSUM(0));
        f1 += __expf(-ROWSUM(1));
        f2 += __expf(-ROWSUM(2));
        f3 += __expf(-ROWSUM(3));
#undef ROWSUM
    }
    atomicAdd(&out[(tid +   0) * 1056 + 1024 + k], f0);
    atomicAdd(&out[(tid + 256) * 1056 + 1024 + k], f1);
    atomicAdd(&out[(tid + 512) * 1056 + 1024 + k], f2);
    atomicAdd(&out[(tid + 768) * 1056 + 1024 + k], f3);
}

extern "C" void kernel_launch(void* const* d_in, const int* in_sizes, int n_in,
                              void* d_out, int out_size, void* d_ws, size_t ws_size,
                              hipStream_t stream) {
    const float* x = (const float*)d_in[0];
    const float* W = (const float*)d_in[1];
    float* out  = (float*)d_out;
    float* act2 = (float*)d_ws;    // 2 MB

    gemm_k<<<1024, 256, 0, stream>>>(x, W, act2, out);
    pairwise_k<<<dim3(32, 32), 256, 0, stream>>>(act2, out);
}

// Round 8
// 107.201 us; speedup vs baseline: 2.4717x; 1.5134x over previous
//
#include <hip/hip_runtime.h>
#include <hip/hip_bf16.h>
#include <hip/hip_fp16.h>

#define BATCH 1024
#define INPUT_DIM 1024
#define NBK 32
#define KDIM 16

typedef __attribute__((ext_vector_type(8))) short short8;
typedef __attribute__((ext_vector_type(8))) unsigned short ushort8;
typedef __attribute__((ext_vector_type(4))) float f32x4;

static __device__ __forceinline__ unsigned short f2bf(float f) {
    union { float f; unsigned u; } v; v.f = f;
    unsigned r = v.u + 0x7fffu + ((v.u >> 16) & 1u);   // RNE
    return (unsigned short)(r >> 16);
}

// ---------------------------------------------------------------------------
// Kernel 1 (prep): blocks [0,512): x fp32 -> xb bf16 AND x -> out[b][0:1024].
//                  blocks [512,640): W[k][d][m] -> Wt[k][m][d] bf16.
// (R4/R6-proven bodies.)
// ---------------------------------------------------------------------------
__global__ __launch_bounds__(256) void prep_k(const float* __restrict__ x,
                                              const float* __restrict__ W,
                                              unsigned short* __restrict__ xb,
                                              unsigned short* __restrict__ wt,
                                              float* __restrict__ out) {
    const int blk = blockIdx.x;
    const int tid = threadIdx.x;
    if (blk < 512) {
        const int i = (blk * 256 + tid) * 8;
        float4 v0 = *(const float4*)(x + i);
        float4 v1 = *(const float4*)(x + i + 4);
        ushort8 o;
        o[0] = f2bf(v0.x); o[1] = f2bf(v0.y); o[2] = f2bf(v0.z); o[3] = f2bf(v0.w);
        o[4] = f2bf(v1.x); o[5] = f2bf(v1.y); o[6] = f2bf(v1.z); o[7] = f2bf(v1.w);
        *(ushort8*)(xb + i) = o;
        const int b = i >> 10;
        const int d = i & 1023;
        float* op = out + b * 1056 + d;
        *(float4*)(op)     = v0;
        *(float4*)(op + 4) = v1;
    } else {
        const int b2 = blk - 512;                  // 0..127
        const int k  = b2 >> 2;                    // 0..31
        const int d  = (b2 & 3) * 256 + tid;
        const float* src = W + (k * INPUT_DIM + d) * KDIM;  // 16 contiguous floats
        float4 v0 = *(const float4*)(src + 0);
        float4 v1 = *(const float4*)(src + 4);
        float4 v2 = *(const float4*)(src + 8);
        float4 v3 = *(const float4*)(src + 12);
        unsigned short* dst = wt + k * (KDIM * INPUT_DIM) + d;  // stride 1024 per m
        dst[0 * INPUT_DIM]  = f2bf(v0.x); dst[1 * INPUT_DIM]  = f2bf(v0.y);
        dst[2 * INPUT_DIM]  = f2bf(v0.z); dst[3 * INPUT_DIM]  = f2bf(v0.w);
        dst[4 * INPUT_DIM]  = f2bf(v1.x); dst[5 * INPUT_DIM]  = f2bf(v1.y);
        dst[6 * INPUT_DIM]  = f2bf(v1.z); dst[7 * INPUT_DIM]  = f2bf(v1.w);
        dst[8 * INPUT_DIM]  = f2bf(v2.x); dst[9 * INPUT_DIM]  = f2bf(v2.y);
        dst[10 * INPUT_DIM] = f2bf(v2.z); dst[11 * INPUT_DIM] = f2bf(v2.w);
        dst[12 * INPUT_DIM] = f2bf(v3.x); dst[13 * INPUT_DIM] = f2bf(v3.y);
        dst[14 * INPUT_DIM] = f2bf(v3.z); dst[15 * INPUT_DIM] = f2bf(v3.w);
    }
}

// ---------------------------------------------------------------------------
// Kernel 2 (gemm): act2h[k][b][m] (f16!) via bf16 MFMA 16x16x32 from xb/wt.
// 1024 blocks x 256 thr; 4 waves split d 4-way (8 slabs of 32), LDS reduce.
// Structure identical to R6-fused gemm_tile (proven); epilogue converts to f16.
// ---------------------------------------------------------------------------
__global__ __launch_bounds__(256) void gemm_k(const unsigned short* __restrict__ xb,
                                              const unsigned short* __restrict__ wt,
                                              __half* __restrict__ act2h) {
    __shared__ float lds[1536];
    const int bid  = blockIdx.x;
    const int tid  = threadIdx.x;
    const int k    = bid >> 5;
    const int b0   = (bid & 31) * 32;
    const int lane = tid & 63;
    const int w4   = tid >> 6;                 // 0..3: d-quarter
    const int m16  = lane & 15;
    const int quad = lane >> 4;

    const unsigned short* a0p = xb + (b0 + m16) * INPUT_DIM + w4 * 256 + quad * 8;
    const unsigned short* a1p = a0p + 16 * INPUT_DIM;
    const unsigned short* bp  = wt + k * (KDIM * INPUT_DIM) + m16 * INPUT_DIM
                                   + w4 * 256 + quad * 8;

    f32x4 acc0 = {0.f, 0.f, 0.f, 0.f};
    f32x4 acc1 = {0.f, 0.f, 0.f, 0.f};

    short8 A0 = *(const short8*)a0p;
    short8 A1 = *(const short8*)a1p;
    short8 BV = *(const short8*)bp;

#pragma unroll
    for (int s = 0; s < 8; ++s) {
        const int sp = (s < 7) ? (s + 1) * 32 : 0;   // wrap: dead value, in-bounds
        short8 nA0 = *(const short8*)(a0p + sp);
        short8 nA1 = *(const short8*)(a1p + sp);
        short8 nBV = *(const short8*)(bp + sp);
        acc0 = __builtin_amdgcn_mfma_f32_16x16x32_bf16(A0, BV, acc0, 0, 0, 0);
        acc1 = __builtin_amdgcn_mfma_f32_16x16x32_bf16(A1, BV, acc1, 0, 0, 0);
        A0 = nA0; A1 = nA1; BV = nBV;
    }

    if (w4 > 0) {
        float* r = &lds[(w4 - 1) * 512 + lane * 8];
        *(float4*)(r)     = make_float4(acc0[0], acc0[1], acc0[2], acc0[3]);
        *(float4*)(r + 4) = make_float4(acc1[0], acc1[1], acc1[2], acc1[3]);
    }
    __syncthreads();
    if (w4 == 0) {
#pragma unroll
        for (int j = 0; j < 3; ++j) {
            const float* r = &lds[j * 512 + lane * 8];
            float4 p0 = *(const float4*)(r);
            float4 p1 = *(const float4*)(r + 4);
            acc0[0] += p0.x; acc0[1] += p0.y; acc0[2] += p0.z; acc0[3] += p0.w;
            acc1[0] += p1.x; acc1[1] += p1.y; acc1[2] += p1.z; acc1[3] += p1.w;
        }
        const int row0 = b0 + quad * 4;        // C/D: col=lane&15, row=quad*4+r
#pragma unroll
        for (int r = 0; r < 4; ++r) {
            act2h[(k * BATCH + row0 + r) * KDIM + m16]      = __float2half(acc0[r]);
            act2h[(k * BATCH + row0 + 16 + r) * KDIM + m16] = __float2half(acc1[r]);
        }
    }
}

// ---------------------------------------------------------------------------
// Kernel 3 (pairwise): packed-f16 inner loop, 4 b-rows/thread, coalesced
// stores to part (NO atomics — R7 showed scattered atomics cost ~45 us).
// grid = (chunk=32, k=32) = 1024 blocks x 256 thr. LDS: 32 f16 c-rows (1 KB),
// all-lane broadcast reads (2x ds_read_b128 per c-row).
// Per pair: 8x (v_pk_sub + v_and(abs) + v_pk_add) vs 32 scalar fp32 ops.
// ---------------------------------------------------------------------------
__global__ __launch_bounds__(256) void pairwise_k(const __half* __restrict__ act2h,
                                                  float* __restrict__ part) {
    __shared__ __half2 cs[32 * 8];  // 1 KB: 32 rows x 16 halves
    const int tid = threadIdx.x;
    const int k   = blockIdx.y;
    const int c0  = blockIdx.x * 32;
    const __half* base = act2h + k * (BATCH * KDIM);

    if (tid < 64) ((float4*)cs)[tid] = ((const float4*)(base + c0 * KDIM))[tid];

    __half2 a2[4][8];
#pragma unroll
    for (int r = 0; r < 4; ++r) {
        const float4* src = (const float4*)(base + (tid + r * 256) * KDIM);
        union { float4 f; __half2 h[4]; } u0, u1;
        u0.f = src[0]; u1.f = src[1];
#pragma unroll
        for (int j = 0; j < 4; ++j) { a2[r][j] = u0.h[j]; a2[r][4 + j] = u1.h[j]; }
    }
    __syncthreads();

    float f0 = 0.f, f1 = 0.f, f2 = 0.f, f3 = 0.f;
#pragma unroll 2
    for (int c = 0; c < 32; ++c) {
        union { float4 f; __half2 h[4]; } q0, q1;
        q0.f = *(const float4*)&cs[c * 8];
        q1.f = *(const float4*)&cs[c * 8 + 4];
        __half2 cr[8];
#pragma unroll
        for (int j = 0; j < 4; ++j) { cr[j] = q0.h[j]; cr[4 + j] = q1.h[j]; }

        __half2 s0 = __float2half2_rn(0.f), s1 = s0, s2 = s0, s3 = s0;
#pragma unroll
        for (int j = 0; j < 8; ++j) {
            s0 = __hadd2(s0, __habs2(__hsub2(a2[0][j], cr[j])));
            s1 = __hadd2(s1, __habs2(__hsub2(a2[1][j], cr[j])));
            s2 = __hadd2(s2, __habs2(__hsub2(a2[2][j], cr[j])));
            s3 = __hadd2(s3, __habs2(__hsub2(a2[3][j], cr[j])));
        }
        f0 += __expf(-(__low2float(s0) + __high2float(s0)));
        f1 += __expf(-(__low2float(s1) + __high2float(s1)));
        f2 += __expf(-(__low2float(s2) + __high2float(s2)));
        f3 += __expf(-(__low2float(s3) + __high2float(s3)));
    }
    float* p = part + blockIdx.x * (NBK * BATCH) + k * BATCH + tid;
    p[0]   = f0;
    p[256] = f1;
    p[512] = f2;
    p[768] = f3;
}

// ---------------------------------------------------------------------------
// Kernel 4: out[b][1024+k] = sum over 32 chunks of part[ch][k][b] (R4-proven).
// ---------------------------------------------------------------------------
__global__ __launch_bounds__(256) void combine_k(const float* __restrict__ part,
                                                 float* __restrict__ out) {
    const int t = blockIdx.x * 256 + threadIdx.x;   // k*1024 + b, t < 32768
    const int k = t >> 10;
    const int b = t & 1023;
    float s = 0.f;
#pragma unroll
    for (int i = 0; i < 32; ++i) s += part[i * (NBK * BATCH) + t];
    out[b * 1056 + 1024 + k] = s;
}

extern "C" void kernel_launch(void* const* d_in, const int* in_sizes, int n_in,
                              void* d_out, int out_size, void* d_ws, size_t ws_size,
                              hipStream_t stream) {
    const float* x = (const float*)d_in[0];
    const float* W = (const float*)d_in[1];
    float* out = (float*)d_out;

    unsigned short* xb = (unsigned short*)d_ws;                         // 2 MB
    unsigned short* wt = (unsigned short*)((char*)d_ws + 2*1024*1024);  // 1 MB
    __half* act2h      = (__half*)((char*)d_ws + 3*1024*1024);          // 1 MB
    float* part        = (float*)((char*)d_ws + 4*1024*1024);           // 4 MB

    prep_k<<<640, 256, 0, stream>>>(x, W, xb, wt, out);
    gemm_k<<<1024, 256, 0, stream>>>(xb, wt, act2h);
    pairwise_k<<<dim3(32, 32), 256, 0, stream>>>(act2h, part);
    combine_k<<<128, 256, 0, stream>>>(part, out);
}

// Round 9
// 96.456 us; speedup vs baseline: 2.7470x; 1.1114x over previous
//
#include <hip/hip_runtime.h>
#include <hip/hip_bf16.h>

#define BATCH 1024
#define INPUT_DIM 1024
#define NBK 32
#define KDIM 16

typedef __attribute__((ext_vector_type(8))) short short8;
typedef __attribute__((ext_vector_type(4))) float f32x4;

// u16 quantization of act: u = round(act*QS) + 32768. Bias cancels in |a-c|;
// SAD accumulates integer L1; exp(-L1/QS) = exp2(L1_int * (-log2e/QS)).
#define QS 2048.0f
#define EXPC (-7.0444191e-4f)   // -log2(e)/2048

#if __has_builtin(__builtin_amdgcn_sad_u16)
__device__ __forceinline__ unsigned int sadu16(unsigned int a, unsigned int b,
                                               unsigned int acc) {
    return __builtin_amdgcn_sad_u16(a, b, acc);
}
#else
__device__ __forceinline__ unsigned int sadu16(unsigned int a, unsigned int b,
                                               unsigned int acc) {
    int d0 = (int)(a & 0xFFFFu) - (int)(b & 0xFFFFu);
    int d1 = (int)(a >> 16)     - (int)(b >> 16);
    return acc + (unsigned int)(d0 < 0 ? -d0 : d0) + (unsigned int)(d1 < 0 ? -d1 : d1);
}
#endif

// pack two fp32 -> one u32 holding two bf16 (truncation): 1 v_perm_b32.
// lo16 = hi half of `lo`, hi16 = hi half of `hi`.
__device__ __forceinline__ unsigned int pk_bf16_trunc(float lo, float hi) {
    union { float f; unsigned u; } a, b;
    a.f = lo; b.f = hi;
    return __builtin_amdgcn_perm(b.u, a.u, 0x07060302u);
}

// ---------------------------------------------------------------------------
// Kernel 1: act2u[k][b][m] (u16-quantized) via bf16 MFMA 16x16x32, reading
// x and W directly in fp32 (perm-truncation to bf16 in-register — no prep
// pass). Grid (k*32+btile)=1024 blocks x 256 thr; 4 waves split d 4-way
// (8 slabs of 32), LDS cross-wave reduce (R4/R7-proven structure).
// Side job: each block copies a 4 KB slice of x -> out[b][0:1024].
// A lane: x[b0+(lane&15)][d0+(lane>>4)*8+j]; B lane: W[k][d..][lane&15];
// C/D: col=lane&15, row=(lane>>4)*4+reg. (All layouts validated R2-R8.)
// ---------------------------------------------------------------------------
__global__ __launch_bounds__(256) void gemm_k(const float* __restrict__ x,
                                              const float* __restrict__ W,
                                              unsigned short* __restrict__ act2u,
                                              float* __restrict__ out) {
    __shared__ float lds[1536];
    const int bid  = blockIdx.x;
    const int tid  = threadIdx.x;
    const int k    = bid >> 5;
    const int b0   = (bid & 31) * 32;
    const int lane = tid & 63;
    const int w4   = tid >> 6;                 // 0..3: d-quarter
    const int m16  = lane & 15;
    const int quad = lane >> 4;

    // side job: copy x slice into out (each block: 1024 floats, disjoint)
    {
        const int i = bid * 1024 + tid * 4;
        float4 v = *(const float4*)(x + i);
        const int b = i >> 10;
        const int d = i & 1023;
        *(float4*)(out + b * 1056 + d) = v;
    }

    const float* xa0 = x + (b0 + m16) * INPUT_DIM + w4 * 256 + quad * 8;
    const float* xa1 = xa0 + 16 * INPUT_DIM;
    const float* wb  = W + k * (INPUT_DIM * KDIM) + (w4 * 256 + quad * 8) * KDIM + m16;

    f32x4 acc0 = {0.f, 0.f, 0.f, 0.f};
    f32x4 acc1 = {0.f, 0.f, 0.f, 0.f};

#pragma unroll
    for (int s = 0; s < 8; ++s) {
        const float* pa0 = xa0 + s * 32;
        const float* pa1 = xa1 + s * 32;
        const float* pb  = wb + s * 32 * KDIM;
        float4 a0l = *(const float4*)(pa0);
        float4 a0h = *(const float4*)(pa0 + 4);
        float4 a1l = *(const float4*)(pa1);
        float4 a1h = *(const float4*)(pa1 + 4);
        float b0w = pb[0 * KDIM], b1w = pb[1 * KDIM];
        float b2w = pb[2 * KDIM], b3w = pb[3 * KDIM];
        float b4w = pb[4 * KDIM], b5w = pb[5 * KDIM];
        float b6w = pb[6 * KDIM], b7w = pb[7 * KDIM];
        union { unsigned int u[4]; short8 s8; } A0, A1, BV;
        A0.u[0] = pk_bf16_trunc(a0l.x, a0l.y); A0.u[1] = pk_bf16_trunc(a0l.z, a0l.w);
        A0.u[2] = pk_bf16_trunc(a0h.x, a0h.y); A0.u[3] = pk_bf16_trunc(a0h.z, a0h.w);
        A1.u[0] = pk_bf16_trunc(a1l.x, a1l.y); A1.u[1] = pk_bf16_trunc(a1l.z, a1l.w);
        A1.u[2] = pk_bf16_trunc(a1h.x, a1h.y); A1.u[3] = pk_bf16_trunc(a1h.z, a1h.w);
        BV.u[0] = pk_bf16_trunc(b0w, b1w);     BV.u[1] = pk_bf16_trunc(b2w, b3w);
        BV.u[2] = pk_bf16_trunc(b4w, b5w);     BV.u[3] = pk_bf16_trunc(b6w, b7w);
        acc0 = __builtin_amdgcn_mfma_f32_16x16x32_bf16(A0.s8, BV.s8, acc0, 0, 0, 0);
        acc1 = __builtin_amdgcn_mfma_f32_16x16x32_bf16(A1.s8, BV.s8, acc1, 0, 0, 0);
    }

    // cross-wave reduce (d-quarters) via LDS, wave0 quantizes + writes u16
    if (w4 > 0) {
        float* r = &lds[(w4 - 1) * 512 + lane * 8];
        *(float4*)(r)     = make_float4(acc0[0], acc0[1], acc0[2], acc0[3]);
        *(float4*)(r + 4) = make_float4(acc1[0], acc1[1], acc1[2], acc1[3]);
    }
    __syncthreads();
    if (w4 == 0) {
#pragma unroll
        for (int j = 0; j < 3; ++j) {
            const float* r = &lds[j * 512 + lane * 8];
            float4 p0 = *(const float4*)(r);
            float4 p1 = *(const float4*)(r + 4);
            acc0[0] += p0.x; acc0[1] += p0.y; acc0[2] += p0.z; acc0[3] += p0.w;
            acc1[0] += p1.x; acc1[1] += p1.y; acc1[2] += p1.z; acc1[3] += p1.w;
        }
        const int row0 = b0 + quad * 4;
#pragma unroll
        for (int r = 0; r < 4; ++r) {
            float q0 = fminf(fmaxf(acc0[r] * QS, -30000.f), 30000.f);
            float q1 = fminf(fmaxf(acc1[r] * QS, -30000.f), 30000.f);
            act2u[(k * BATCH + row0 + r) * KDIM + m16] =
                (unsigned short)(32768 + (int)rintf(q0));
            act2u[(k * BATCH + row0 + 16 + r) * KDIM + m16] =
                (unsigned short)(32768 + (int)rintf(q1));
        }
    }
}

// ---------------------------------------------------------------------------
// Kernel 2: pairwise features via v_sad_u16 — 1 instr per 2 elements with
// built-in accumulation (vs 3 packed-f16 ops). 4 b-rows/thread.
// grid = (chunk=32, k=32) = 1024 blocks x 256 thr. LDS: 32 u16 c-rows (1 KB),
// all-lane broadcast reads. Coalesced stores to part (no atomics — R7).
// ---------------------------------------------------------------------------
__global__ __launch_bounds__(256) void pairwise_k(const unsigned short* __restrict__ act2u,
                                                  float* __restrict__ part) {
    __shared__ unsigned int cs[32 * 8];  // 1 KB: 32 rows x 16 u16
    const int tid = threadIdx.x;
    const int k   = blockIdx.y;
    const int c0  = blockIdx.x * 32;
    const unsigned short* base = act2u + k * (BATCH * KDIM);

    if (tid < 64) ((uint4*)cs)[tid] = ((const uint4*)(base + c0 * KDIM))[tid];

    unsigned int a[4][8];
#pragma unroll
    for (int r = 0; r < 4; ++r) {
        const uint4* src = (const uint4*)(base + (tid + r * 256) * KDIM);
        uint4 u0 = src[0], u1 = src[1];
        a[r][0] = u0.x; a[r][1] = u0.y; a[r][2] = u0.z; a[r][3] = u0.w;
        a[r][4] = u1.x; a[r][5] = u1.y; a[r][6] = u1.z; a[r][7] = u1.w;
    }
    __syncthreads();

    float f0 = 0.f, f1 = 0.f, f2 = 0.f, f3 = 0.f;
#pragma unroll 2
    for (int c = 0; c < 32; ++c) {
        uint4 q0 = *(const uint4*)&cs[c * 8];
        uint4 q1 = *(const uint4*)&cs[c * 8 + 4];
        unsigned int cr[8] = {q0.x, q0.y, q0.z, q0.w, q1.x, q1.y, q1.z, q1.w};
        unsigned int s0 = 0u, s1 = 0u, s2 = 0u, s3 = 0u;
#pragma unroll
        for (int j = 0; j < 8; ++j) {
            s0 = sadu16(a[0][j], cr[j], s0);
            s1 = sadu16(a[1][j], cr[j], s1);
            s2 = sadu16(a[2][j], cr[j], s2);
            s3 = sadu16(a[3][j], cr[j], s3);
        }
        f0 += exp2f((float)s0 * EXPC);
        f1 += exp2f((float)s1 * EXPC);
        f2 += exp2f((float)s2 * EXPC);
        f3 += exp2f((float)s3 * EXPC);
    }
    float* p = part + blockIdx.x * (NBK * BATCH) + k * BATCH + tid;
    p[0]   = f0;
    p[256] = f1;
    p[512] = f2;
    p[768] = f3;
}

// ---------------------------------------------------------------------------
// Kernel 3: out[b][1024+k] = sum over 32 chunks of part[ch][k][b] (proven).
// ---------------------------------------------------------------------------
__global__ __launch_bounds__(256) void combine_k(const float* __restrict__ part,
                                                 float* __restrict__ out) {
    const int t = blockIdx.x * 256 + threadIdx.x;   // k*1024 + b, t < 32768
    const int k = t >> 10;
    const int b = t & 1023;
    float s = 0.f;
#pragma unroll
    for (int i = 0; i < 32; ++i) s += part[i * (NBK * BATCH) + t];
    out[b * 1056 + 1024 + k] = s;
}

extern "C" void kernel_launch(void* const* d_in, const int* in_sizes, int n_in,
                              void* d_out, int out_size, void* d_ws, size_t ws_size,
                              hipStream_t stream) {
    const float* x = (const float*)d_in[0];
    const float* W = (const float*)d_in[1];
    float* out = (float*)d_out;

    unsigned short* act2u = (unsigned short*)d_ws;                  // 1 MB
    float* part = (float*)((char*)d_ws + 1024 * 1024);              // 4 MB

    gemm_k<<<1024, 256, 0, stream>>>(x, W, act2u, out);
    pairwise_k<<<dim3(32, 32), 256, 0, stream>>>(act2u, part);
    combine_k<<<128, 256, 0, stream>>>(part, out);
}